// Round 6
// baseline (1013.219 us; speedup 1.0000x reference)
//
#include <hip/hip_runtime.h>
#include <hip/hip_bf16.h>

#define NODES 32768
#define HD 128
#define NE 524288
#define NR 8
#define NS 262144                          // 4 pass-halves * NODES * 2 keys
#define PASSB 65536                        // keys per pass = NODES*2

typedef unsigned int u32;
typedef unsigned short u16;
typedef __attribute__((ext_vector_type(8))) short bf16x8;
typedef __attribute__((ext_vector_type(4))) float f32x4;

// ---- ws byte offsets ----
#define XH_OFF   (0u)                      // bf16 hi x, 8 MB
#define XL_OFF   (8u<<20)                  // bf16 lo x, 8 MB
#define XH2_OFF  (16u<<20)                 // layer-1 x hi
#define XL2_OFF  (24u<<20)                 // layer-1 x lo
#define ADJ_OFF  (32u<<20)                 // u32 x NE packed (src | row<<15)
#define RP_OFF   (34u<<20)                 // u32 x (NS+1)
#define CUR_OFF  (36u<<20)                 // u32 x NS
#define BSUM_OFF (37u<<20)                 // u32 x 1025
#define BP_OFF   (38u<<20)                 // packed weights bf16

#define BP_LAYER 294912                    // 9*2*16384
#define PP_ELEM  589824                    // pW packed at Bp+PP_ELEM

__device__ __forceinline__ float bflo(u32 u){ union{u32 i;float f;}c; c.i=u<<16; return c.f; }
__device__ __forceinline__ float bfhi(u32 u){ union{u32 i;float f;}c; c.i=u&0xffff0000u; return c.f; }
__device__ __forceinline__ u16 f2bf(float f){
  u32 u=__float_as_uint(f);
  u32 r=u + 0x7fffu + ((u>>16)&1u);
  return (u16)(r>>16);
}
__device__ __forceinline__ float bf2f(u16 h){ return __uint_as_float(((u32)h)<<16); }

__device__ __forceinline__ void gl_lds16(const void* g, void* l){
  __builtin_amdgcn_global_load_lds((const __attribute__((address_space(1))) u32*)g,
                                   (__attribute__((address_space(3))) u32*)l, 16, 0, 0);
}

// ---------------- weight prep: 2 layers x 9 tiles (8 rel + self) + pW, hi/lo segs ----
__global__ void prep_w(const float* __restrict__ rW, const float* __restrict__ sW,
                       const float* __restrict__ pWg, u16* __restrict__ Bp)
{
  int idx=blockIdx.x*256+threadIdx.x;           // 311296 total
  if(idx<294912){
    int l=idx/147456;
    int rem=idx%147456;
    int t=rem>>14;
    int kn=rem&16383;
    int k=kn>>7, n=kn&127;
    float w;
    if(t<8) w=rW[(((size_t)l*NR+t)*HD+n)*HD+k];
    else    w=sW[((size_t)l*HD+n)*HD+k];
    u16* base=Bp+(size_t)l*BP_LAYER+(size_t)t*32768;
    int ks=k>>5, q=(k>>3)&3, j=k&7;
    size_t off=((size_t)ks*128+n)*32+q*8+j;
    u16 hb=f2bf(w);
    u16 lb=f2bf(w-bf2f(hb));
    base[off]=hb;
    base[off+16384]=lb;
  } else {
    int kn=idx-294912;
    int k=kn>>7, n=kn&127;
    float w=pWg[(size_t)n*HD+k];
    u16* base=Bp+PP_ELEM;
    int ks=k>>5, q=(k>>3)&3, j=k&7;
    size_t off=((size_t)ks*128+n)*32+q*8+j;
    u16 hb=f2bf(w);
    u16 lb=f2bf(w-bf2f(hb));
    base[off]=hb;
    base[off+16384]=lb;
  }
}

// ---------------- embed_mfma: x = (cemb[cid]+kemb[kid]) @ pW^T + pb -> xh/xl ----------
__global__ __launch_bounds__(256,2) void embed_mfma(
    const int* __restrict__ cid, const int* __restrict__ kid,
    const float* __restrict__ cemb, const float* __restrict__ kemb,
    const u16* __restrict__ PP, const float* __restrict__ pb,
    u16* __restrict__ xh, u16* __restrict__ xl)
{
  __shared__ u16 Atile[2][128*128];   // [0]=hi [1]=lo, 64 KB, XOR-16 swizzle
  const int tid=threadIdx.x;
  const int wave=tid>>6, lane=tid&63;
  const int wm=wave>>1, wn=wave&1;
  const int q=lane>>4;
  const int d0=blockIdx.x*128;

  { int r=tid>>1, half=tid&1;
    int ci=cid[d0+r], ki=kid[d0+r];
    const float* cp=cemb+(size_t)ci*HD+half*64;
    const float* kp=kemb+(size_t)ki*HD+half*64;
#pragma unroll
    for(int cc=0;cc<8;cc++){
      float4 a0=*(const float4*)(cp+cc*8);
      float4 a1=*(const float4*)(cp+cc*8+4);
      float4 b0=*(const float4*)(kp+cc*8);
      float4 b1=*(const float4*)(kp+cc*8+4);
      float v[8]={a0.x+b0.x,a0.y+b0.y,a0.z+b0.z,a0.w+b0.w,
                  a1.x+b1.x,a1.y+b1.y,a1.z+b1.z,a1.w+b1.w};
      u16 hb[8], lb[8];
#pragma unroll
      for(int j=0;j<8;j++){ hb[j]=f2bf(v[j]); lb[j]=f2bf(v[j]-bf2f(hb[j])); }
      int chunk=half*8+cc;
      int dst=r*128+(chunk^(r&15))*8;
      uint4 hv={(u32)hb[0]|((u32)hb[1]<<16),(u32)hb[2]|((u32)hb[3]<<16),
                (u32)hb[4]|((u32)hb[5]<<16),(u32)hb[6]|((u32)hb[7]<<16)};
      uint4 lv={(u32)lb[0]|((u32)lb[1]<<16),(u32)lb[2]|((u32)lb[3]<<16),
                (u32)lb[4]|((u32)lb[5]<<16),(u32)lb[6]|((u32)lb[7]<<16)};
      *(uint4*)&Atile[0][dst]=hv;
      *(uint4*)&Atile[1][dst]=lv;
    }
  }
  __syncthreads();

  f32x4 acc[4][4];
#pragma unroll
  for(int a=0;a<4;a++)
#pragma unroll
    for(int b=0;b<4;b++) acc[a][b]=(f32x4){0.f,0.f,0.f,0.f};

#pragma unroll
  for(int ks=0;ks<4;ks++){
    bf16x8 ah[4];
#pragma unroll
    for(int tm=0;tm<4;tm++){
      int m=wm*64+tm*16+(lane&15);
      ah[tm]=*(const bf16x8*)&Atile[0][m*128+(((ks*4)+q)^(m&15))*8];
    }
#pragma unroll
    for(int s=0;s<2;s++){
      const u16* Bb=PP+s*16384;
#pragma unroll
      for(int tn=0;tn<4;tn++){
        int n=wn*64+tn*16+(lane&15);
        bf16x8 bfr=*(const bf16x8*)&Bb[((size_t)ks*128+n)*32+q*8];
#pragma unroll
        for(int tm=0;tm<4;tm++)
          acc[tm][tn]=__builtin_amdgcn_mfma_f32_16x16x32_bf16(ah[tm],bfr,acc[tm][tn],0,0,0);
      }
    }
  }
#pragma unroll
  for(int ks=0;ks<4;ks++){
    bf16x8 al[4];
#pragma unroll
    for(int tm=0;tm<4;tm++){
      int m=wm*64+tm*16+(lane&15);
      al[tm]=*(const bf16x8*)&Atile[1][m*128+(((ks*4)+q)^(m&15))*8];
    }
#pragma unroll
    for(int tn=0;tn<4;tn++){
      int n=wn*64+tn*16+(lane&15);
      bf16x8 bfr=*(const bf16x8*)&PP[((size_t)ks*128+n)*32+q*8];
#pragma unroll
      for(int tm=0;tm<4;tm++)
        acc[tm][tn]=__builtin_amdgcn_mfma_f32_16x16x32_bf16(al[tm],bfr,acc[tm][tn],0,0,0);
    }
  }

  // ---- epilogue: +pb, hi/lo split into dead Atile (swz bits5-6), linear dwordx4 out ----
  __syncthreads();
  { u16* Sh=(u16*)Atile[0];
    u16* Sl=(u16*)Atile[1];
#pragma unroll
    for(int tn=0;tn<4;tn++){
      int n=wn*64+tn*16+(lane&15);
      float b=pb[n];
#pragma unroll
      for(int tm=0;tm<4;tm++){
        int rbase=wm*64+tm*16+q*4;
#pragma unroll
        for(int r=0;r<4;r++){
          float v=acc[tm][tn][r]+b;
          u16 hb=f2bf(v);
          u16 lb=f2bf(v-bf2f(hb));
          int row=rbase+r;
          u32 ab=(u32)(row*256+n*2);
          ab^=((u32)((row>>2)&3))<<5;
          Sh[ab>>1]=hb;
          Sl[ab>>1]=lb;
        }
      }
    }
  }
  __syncthreads();
  { const char* S0=(const char*)Atile[0];
    const char* S1=(const char*)Atile[1];
    char* xhb=(char*)(xh+(size_t)d0*HD);
    char* xlb=(char*)(xl+(size_t)d0*HD);
#pragma unroll
    for(int i=0;i<8;i++){
      u32 byte=(u32)(i*256+tid)*16;       // 32 KB tile, 16 lanes = one 256B row
      u32 row=byte>>8;
      u32 lb2=byte^((((row>>2)&3))<<5);
      *(uint4*)(xhb+byte)=*(const uint4*)(S0+lb2);
      *(uint4*)(xlb+byte)=*(const uint4*)(S1+lb2);
    }
  }
}

// ---------------- CSR build, key = (et>>1)*PASSB + dst*2 + (et&1) ----------------
__global__ void count_deg2(const int* __restrict__ dst, const int* __restrict__ et,
                           u32* __restrict__ cnt){
  int e=blockIdx.x*256+threadIdx.x;
  int t=et[e];
  int key=(t>>1)*PASSB + dst[e]*2 + (t&1);
  atomicAdd(&cnt[key],1u);
}

__global__ void scan1(u32* __restrict__ cnt, u32* __restrict__ rp, u32* __restrict__ bsum){
  __shared__ u32 sh[256];
  int t=threadIdx.x; int base=blockIdx.x*256;
  u32 v=cnt[base+t]; sh[t]=v;
  cnt[base+t]=0u;                       // re-zero cur for scatter
  __syncthreads();
  for(int off=1;off<256;off<<=1){
    u32 tv=(t>=off)?sh[t-off]:0u; __syncthreads();
    sh[t]+=tv; __syncthreads();
  }
  rp[base+t]=sh[t]-v;
  if(t==255) bsum[blockIdx.x]=sh[255];
}

__global__ void scan2b(u32* __restrict__ bsum, u32* __restrict__ rp){
  __shared__ u32 sh[256];
  int t=threadIdx.x;
  u32 v0=bsum[t*4+0],v1=bsum[t*4+1],v2=bsum[t*4+2],v3=bsum[t*4+3];
  u32 s=v0+v1+v2+v3;
  sh[t]=s; __syncthreads();
  for(int off=1;off<256;off<<=1){
    u32 tv=(t>=off)?sh[t-off]:0u; __syncthreads();
    sh[t]+=tv; __syncthreads();
  }
  u32 ex=sh[t]-s;
  bsum[t*4+0]=ex; bsum[t*4+1]=ex+v0; bsum[t*4+2]=ex+v0+v1; bsum[t*4+3]=ex+v0+v1+v2;
  if(t==0) rp[NS]=NE;
  if(t==255) bsum[1024]=0u;
}

__global__ void scatter_edges2(const int* __restrict__ src, const int* __restrict__ dst,
                               const int* __restrict__ et, const u32* __restrict__ rp,
                               const u32* __restrict__ bsum,
                               u32* __restrict__ cur, u32* __restrict__ adj){
  int e=blockIdx.x*256+threadIdx.x;
  int t=et[e];
  int d=dst[e];
  int key=(t>>1)*PASSB + d*2 + (t&1);
  u32 pos=atomicAdd(&cur[key],1u);
  u32 val=(u32)src[e] | (((u32)(((t&1)<<6)|(d&63)))<<15);   // src | localrow<<15 (7b)
  adj[rp[key]+bsum[key>>8]+pos]=val;
}

// ---------------- fused_layer v2: branchless ds_add_f32 gather ----------------
// 64-dst blocks, 512 thr (8 waves), 2 blocks/CU. Per pass: zero f32 tile -> range-
// sliced gather (scalar-base loads 16-deep dbl-buffered, 2x atomicAdd LDS per edge)
// -> in-reg f32->bf16 hi/lo trunc-split conversion (swizzled) -> GEMM 2 rels (2x4
// wave tiling). Then self-GEMM + fused /deg + bias + relu + hi/lo out.
__global__ __launch_bounds__(512,4) void fused_layer(
    const u16* __restrict__ xh, const u16* __restrict__ xl,
    const u16* __restrict__ Bp,
    const u32* __restrict__ rp, const u32* __restrict__ bsum,
    const u32* __restrict__ adj,
    const float* __restrict__ sb, const int* __restrict__ mask,
    u16* __restrict__ oh, u16* __restrict__ ol, float* __restrict__ outf, int last)
{
  __shared__ float A32[128*128];    // 64 KB f32 accum; reused as bf16 hi(32K)+lo(32K)
  __shared__ float sdeg[64];
  u16* As16=(u16*)A32;
  u32* As32w=(u32*)A32;
  const int tid=threadIdx.x;
  const int wave=tid>>6, lane=tid&63;
  const int wm=wave>>2, wn=wave&3;
  const int q=lane>>4;
  const int d0=blockIdx.x*64;
  const u32* xh32=(const u32*)xh;

  f32x4 accR[2][2];
#pragma unroll
  for(int a=0;a<2;a++)
#pragma unroll
    for(int b=0;b<2;b++) accR[a][b]=(f32x4){0.f,0.f,0.f,0.f};

#define PROC(W,H) do{ \
    u32 row_=(W)>>15; \
    float* rb_=&A32[row_*128+lane]; \
    atomicAdd(rb_,    bflo(H)); \
    atomicAdd(rb_+64, bfhi(H)); \
  }while(0)

  for(int p=0;p<4;p++){
    // ---- zero f32 tile ----
    { uint4 zz={0u,0u,0u,0u};
#pragma unroll
      for(int k2=0;k2<8;k2++) *(uint4*)&A32[k2*2048+tid*4]=zz;
    }
    __syncthreads();
    // ---- gather: range-sliced, branchless, 16-deep double-buffered ----
    { u32 kb=(u32)(p*PASSB + d0*2);
      u32 ke=kb+128u;
      u32 beg=rp[kb]+bsum[kb>>8];
      u32 end=rp[ke]+bsum[ke>>8];
      u32 len=end-beg;
      u32 wbeg=beg + (len*(u32)wave)/8u;
      u32 wend=beg + (len*(u32)(wave+1))/8u;
      for(u32 base=wbeg; base<wend; base+=64u){
        int nk=(int)(wend-base); if(nk>64) nk=64;
        u32 adjv=(lane<nk)?adj[base+lane]:0u;
        u32 hA[16], hB[16];
#pragma unroll
        for(int j=0;j<16;j++) if(j<nk){
          u32 w=(u32)__builtin_amdgcn_readlane((int)adjv,j);
          hA[j]=xh32[(size_t)(w&0x7fffu)*64+lane];
        }
        for(int i0=0;i0<nk;i0+=32){
#pragma unroll
          for(int j=0;j<16;j++) if(i0+16+j<nk){
            u32 w=(u32)__builtin_amdgcn_readlane((int)adjv,i0+16+j);
            hB[j]=xh32[(size_t)(w&0x7fffu)*64+lane];
          }
#pragma unroll
          for(int j=0;j<16;j++) if(i0+j<nk){
            u32 w=(u32)__builtin_amdgcn_readlane((int)adjv,i0+j);
            PROC(w,hA[j]);
          }
#pragma unroll
          for(int j=0;j<16;j++) if(i0+32+j<nk){
            u32 w=(u32)__builtin_amdgcn_readlane((int)adjv,i0+32+j);
            hA[j]=xh32[(size_t)(w&0x7fffu)*64+lane];
          }
#pragma unroll
          for(int j=0;j<16;j++) if(i0+16+j<nk){
            u32 w=(u32)__builtin_amdgcn_readlane((int)adjv,i0+16+j);
            PROC(w,hB[j]);
          }
        }
      }
    }
    __syncthreads();
    // ---- conversion: f32 -> bf16 hi/lo (trunc split), read-all then write-all ----
    { float c0[16], c1[16];
#pragma unroll
      for(int r=0;r<16;r++){
        int row=wave*16+r;
        c0[r]=A32[row*128+lane];
        c1[r]=A32[row*128+64+lane];
      }
      __syncthreads();
#pragma unroll
      for(int r=0;r<16;r++){
        int row=wave*16+r;
        u32 u0=__float_as_uint(c0[r]), u1=__float_as_uint(c1[r]);
        u32 hp=(u1&0xffff0000u)|(u0>>16);
        float l0=c0[r]-__uint_as_float(u0&0xffff0000u);
        float l1=c1[r]-__uint_as_float(u1&0xffff0000u);
        u32 lp=(__float_as_uint(l1)&0xffff0000u)|(__float_as_uint(l0)>>16);
        int fw=row*64 + (((lane>>2)^(row&15))<<2) + (lane&3);
        As32w[fw]=hp;
        As32w[8192+fw]=lp;
      }
    }
    __syncthreads();
    // ---- GEMM relations 2p, 2p+1 (2x4 wave tiling) ----
#pragma unroll
    for(int rl=0;rl<2;rl++){
      const u16* Bt=Bp+(size_t)(p*2+rl)*32768;
#pragma unroll
      for(int ks=0;ks<4;ks++){
        bf16x8 ah[2],al[2];
#pragma unroll
        for(int mf=0;mf<2;mf++){
          int ar=rl*64+wm*32+mf*16+(lane&15);
          int off=ar*128+((((ks<<2)+q)^(ar&15))<<3);
          ah[mf]=*(const bf16x8*)&As16[off];
          al[mf]=*(const bf16x8*)&As16[16384+off];
        }
#pragma unroll
        for(int tn=0;tn<2;tn++){
          int n=wn*32+tn*16+(lane&15);
          size_t boff=((size_t)(ks*128+n))*32+q*8;
          bf16x8 bh=*(const bf16x8*)&Bt[boff];
          bf16x8 bl=*(const bf16x8*)&Bt[boff+16384];
#pragma unroll
          for(int mf=0;mf<2;mf++){
            accR[mf][tn]=__builtin_amdgcn_mfma_f32_16x16x32_bf16(ah[mf],bh,accR[mf][tn],0,0,0);
            accR[mf][tn]=__builtin_amdgcn_mfma_f32_16x16x32_bf16(al[mf],bh,accR[mf][tn],0,0,0);
            accR[mf][tn]=__builtin_amdgcn_mfma_f32_16x16x32_bf16(ah[mf],bl,accR[mf][tn],0,0,0);
          }
        }
      }
    }
    __syncthreads();
  }

  // ---- self: stage x rows d0..d0+63 hi/lo into As (linear dest, pre-swz src) ----
#pragma unroll
  for(int i=0;i<2;i++){
    int rbase=wave*8+i*4;
    int r=rbase+(lane>>4);
    int g=(lane&15)^(r&15);
    gl_lds16(xh+(size_t)(d0+r)*HD+g*8, (char*)A32 + rbase*256);
    gl_lds16(xl+(size_t)(d0+r)*HD+g*8, (char*)A32 + 32768 + rbase*256);
  }
  if(tid<64){
    int g=d0+tid; u32 dg=0;
#pragma unroll
    for(int ph=0;ph<4;ph++){
      u32 k=(u32)(ph*PASSB+g*2);
      dg+=(rp[k+2]+bsum[(k+2)>>8])-(rp[k]+bsum[k>>8]);
    }
    sdeg[tid]=1.f/fmaxf((float)dg,1.f);
  }
  __syncthreads();

  f32x4 accS[2][2];
#pragma unroll
  for(int a=0;a<2;a++)
#pragma unroll
    for(int b=0;b<2;b++) accS[a][b]=(f32x4){0.f,0.f,0.f,0.f};
  { const u16* Bt=Bp+(size_t)8*32768;
#pragma unroll
    for(int ks=0;ks<4;ks++){
      bf16x8 ah[2],al[2];
#pragma unroll
      for(int mf=0;mf<2;mf++){
        int ar=wm*32+mf*16+(lane&15);
        int off=ar*128+((((ks<<2)+q)^(ar&15))<<3);
        ah[mf]=*(const bf16x8*)&As16[off];
        al[mf]=*(const bf16x8*)&As16[16384+off];
      }
#pragma unroll
      for(int tn=0;tn<2;tn++){
        int n=wn*32+tn*16+(lane&15);
        size_t boff=((size_t)(ks*128+n))*32+q*8;
        bf16x8 bh=*(const bf16x8*)&Bt[boff];
        bf16x8 bl=*(const bf16x8*)&Bt[boff+16384];
#pragma unroll
        for(int mf=0;mf<2;mf++){
          accS[mf][tn]=__builtin_amdgcn_mfma_f32_16x16x32_bf16(ah[mf],bh,accS[mf][tn],0,0,0);
          accS[mf][tn]=__builtin_amdgcn_mfma_f32_16x16x32_bf16(al[mf],bh,accS[mf][tn],0,0,0);
          accS[mf][tn]=__builtin_amdgcn_mfma_f32_16x16x32_bf16(ah[mf],bl,accS[mf][tn],0,0,0);
        }
      }
    }
  }

  // ---- epilogue: out = relu(accS + sb + accR/deg) ----
#pragma unroll
  for(int tn=0;tn<2;tn++){
    int n=wn*32+tn*16+(lane&15);
    float bb=sb[n];
    if(last){
#pragma unroll
      for(int mf=0;mf<2;mf++)
#pragma unroll
        for(int rr=0;rr<4;rr++){
          int row=wm*32+mf*16+q*4+rr;
          float v=fmaxf(accS[mf][tn][rr]+bb+accR[mf][tn][rr]*sdeg[row],0.f);
          v*=(float)mask[d0+row];
          outf[(size_t)(d0+row)*HD+n]=v;
        }
    } else {
#pragma unroll
      for(int mf=0;mf<2;mf++)
#pragma unroll
        for(int rr=0;rr<4;rr++){
          int row=wm*32+mf*16+q*4+rr;
          float v=fmaxf(accS[mf][tn][rr]+bb+accR[mf][tn][rr]*sdeg[row],0.f);
          u16 hb=f2bf(v);
          u16 lb=f2bf(v-bf2f(hb));
          oh[(size_t)(d0+row)*HD+n]=hb;
          ol[(size_t)(d0+row)*HD+n]=lb;
        }
    }
  }
#undef PROC
}

extern "C" void kernel_launch(void* const* d_in, const int* in_sizes, int n_in,
                              void* d_out, int out_size, void* d_ws, size_t ws_size,
                              hipStream_t stream)
{
  (void)in_sizes; (void)n_in; (void)out_size; (void)ws_size;
  const int*   cid =(const int*)  d_in[0];
  const int*   kid =(const int*)  d_in[1];
  const int*   mask=(const int*)  d_in[2];
  const int*   ei  =(const int*)  d_in[3];
  const int*   et  =(const int*)  d_in[4];
  const float* cemb=(const float*)d_in[5];
  const float* kemb=(const float*)d_in[6];
  const float* pW  =(const float*)d_in[7];
  const float* pb  =(const float*)d_in[8];
  const float* sW  =(const float*)d_in[9];
  const float* sb  =(const float*)d_in[10];
  const float* rW  =(const float*)d_in[11];
  float* out=(float*)d_out;
  char*  ws =(char*)d_ws;

  u16* xh =(u16*)(ws+XH_OFF);
  u16* xl =(u16*)(ws+XL_OFF);
  u16* xh2=(u16*)(ws+XH2_OFF);
  u16* xl2=(u16*)(ws+XL2_OFF);
  u32* adj =(u32*)(ws+ADJ_OFF);
  u32* rp  =(u32*)(ws+RP_OFF);
  u32* cur =(u32*)(ws+CUR_OFF);
  u32* bsum=(u32*)(ws+BSUM_OFF);
  u16* Bp  =(u16*)(ws+BP_OFF);
  const int* srcA=ei;
  const int* dstA=ei+NE;

  hipMemsetAsync(cur,0,NS*sizeof(u32),stream);
  prep_w<<<1216,256,0,stream>>>(rW,sW,pW,Bp);
  embed_mfma<<<NODES/128,256,0,stream>>>(cid,kid,cemb,kemb,Bp+PP_ELEM,pb,xh,xl);
  count_deg2<<<NE/256,256,0,stream>>>(dstA,et,cur);
  scan1<<<NS/256,256,0,stream>>>(cur,rp,bsum);
  scan2b<<<1,256,0,stream>>>(bsum,rp);
  scatter_edges2<<<NE/256,256,0,stream>>>(srcA,dstA,et,rp,bsum,cur,adj);

  fused_layer<<<NODES/64,512,0,stream>>>(xh,xl,Bp,rp,bsum,adj,sb,mask,xh2,xl2,out,0);
  fused_layer<<<NODES/64,512,0,stream>>>(xh2,xl2,Bp+BP_LAYER,rp,bsum,adj,sb+HD,mask,xh,xl,out,1);
}

// Round 7
// 307.372 us; speedup vs baseline: 3.2964x; 3.2964x over previous
//
#include <hip/hip_runtime.h>
#include <hip/hip_bf16.h>

#define NODES 32768
#define HD 128
#define NE 524288
#define NR 8
#define NS 262144                          // 1024 dst-blocks * 256 keys
#define PASSB 65536

typedef unsigned int u32;
typedef unsigned short u16;
typedef __attribute__((ext_vector_type(8))) short bf16x8;
typedef __attribute__((ext_vector_type(4))) float f32x4;

// ---- ws byte offsets ----
#define XH_OFF   (0u)                      // bf16 hi x, 8 MB
#define XL_OFF   (8u<<20)                  // bf16 lo x, 8 MB
#define XH2_OFF  (16u<<20)                 // layer-1 x hi
#define XL2_OFF  (24u<<20)                 // layer-1 x lo
#define ADJ_OFF  (32u<<20)                 // u32 x NE packed (src | row<<15)
#define RP_OFF   (34u<<20)                 // u32 x (NS+1)
#define CUR_OFF  (36u<<20)                 // u32 x NS
#define BSUM_OFF (37u<<20)                 // u32 x 1025
#define BP_OFF   (38u<<20)                 // packed weights bf16

#define BP_LAYER 294912                    // 9*2*16384
#define PP_ELEM  589824                    // pW packed at Bp+PP_ELEM

__device__ __forceinline__ float bflo(u32 u){ union{u32 i;float f;}c; c.i=u<<16; return c.f; }
__device__ __forceinline__ float bfhi(u32 u){ union{u32 i;float f;}c; c.i=u&0xffff0000u; return c.f; }
__device__ __forceinline__ u16 f2bf(float f){
  u32 u=__float_as_uint(f);
  u32 r=u + 0x7fffu + ((u>>16)&1u);
  return (u16)(r>>16);
}
__device__ __forceinline__ float bf2f(u16 h){ return __uint_as_float(((u32)h)<<16); }

__device__ __forceinline__ void gl_lds16(const void* g, void* l){
  __builtin_amdgcn_global_load_lds((const __attribute__((address_space(1))) u32*)g,
                                   (__attribute__((address_space(3))) u32*)l, 16, 0, 0);
}

// ---------------- weight prep: 2 layers x 9 tiles (8 rel + self) + pW, hi/lo segs ----
__global__ void prep_w(const float* __restrict__ rW, const float* __restrict__ sW,
                       const float* __restrict__ pWg, u16* __restrict__ Bp)
{
  int idx=blockIdx.x*256+threadIdx.x;           // 311296 total
  if(idx<294912){
    int l=idx/147456;
    int rem=idx%147456;
    int t=rem>>14;
    int kn=rem&16383;
    int k=kn>>7, n=kn&127;
    float w;
    if(t<8) w=rW[(((size_t)l*NR+t)*HD+n)*HD+k];
    else    w=sW[((size_t)l*HD+n)*HD+k];
    u16* base=Bp+(size_t)l*BP_LAYER+(size_t)t*32768;
    int ks=k>>5, q=(k>>3)&3, j=k&7;
    size_t off=((size_t)ks*128+n)*32+q*8+j;
    u16 hb=f2bf(w);
    u16 lb=f2bf(w-bf2f(hb));
    base[off]=hb;
    base[off+16384]=lb;
  } else {
    int kn=idx-294912;
    int k=kn>>7, n=kn&127;
    float w=pWg[(size_t)n*HD+k];
    u16* base=Bp+PP_ELEM;
    int ks=k>>5, q=(k>>3)&3, j=k&7;
    size_t off=((size_t)ks*128+n)*32+q*8+j;
    u16 hb=f2bf(w);
    u16 lb=f2bf(w-bf2f(hb));
    base[off]=hb;
    base[off+16384]=lb;
  }
}

// ---------------- embed_mfma: x = (cemb[cid]+kemb[kid]) @ pW^T + pb -> xh/xl ----------
__global__ __launch_bounds__(256,2) void embed_mfma(
    const int* __restrict__ cid, const int* __restrict__ kid,
    const float* __restrict__ cemb, const float* __restrict__ kemb,
    const u16* __restrict__ PP, const float* __restrict__ pb,
    u16* __restrict__ xh, u16* __restrict__ xl)
{
  __shared__ u16 Atile[2][128*128];   // [0]=hi [1]=lo, 64 KB, XOR-16 swizzle
  const int tid=threadIdx.x;
  const int wave=tid>>6, lane=tid&63;
  const int wm=wave>>1, wn=wave&1;
  const int q=lane>>4;
  const int d0=blockIdx.x*128;

  { int r=tid>>1, half=tid&1;
    int ci=cid[d0+r], ki=kid[d0+r];
    const float* cp=cemb+(size_t)ci*HD+half*64;
    const float* kp=kemb+(size_t)ki*HD+half*64;
#pragma unroll
    for(int cc=0;cc<8;cc++){
      float4 a0=*(const float4*)(cp+cc*8);
      float4 a1=*(const float4*)(cp+cc*8+4);
      float4 b0=*(const float4*)(kp+cc*8);
      float4 b1=*(const float4*)(kp+cc*8+4);
      float v[8]={a0.x+b0.x,a0.y+b0.y,a0.z+b0.z,a0.w+b0.w,
                  a1.x+b1.x,a1.y+b1.y,a1.z+b1.z,a1.w+b1.w};
      u16 hb[8], lb[8];
#pragma unroll
      for(int j=0;j<8;j++){ hb[j]=f2bf(v[j]); lb[j]=f2bf(v[j]-bf2f(hb[j])); }
      int chunk=half*8+cc;
      int dst=r*128+(chunk^(r&15))*8;
      uint4 hv={(u32)hb[0]|((u32)hb[1]<<16),(u32)hb[2]|((u32)hb[3]<<16),
                (u32)hb[4]|((u32)hb[5]<<16),(u32)hb[6]|((u32)hb[7]<<16)};
      uint4 lv={(u32)lb[0]|((u32)lb[1]<<16),(u32)lb[2]|((u32)lb[3]<<16),
                (u32)lb[4]|((u32)lb[5]<<16),(u32)lb[6]|((u32)lb[7]<<16)};
      *(uint4*)&Atile[0][dst]=hv;
      *(uint4*)&Atile[1][dst]=lv;
    }
  }
  __syncthreads();

  f32x4 acc[4][4];
#pragma unroll
  for(int a=0;a<4;a++)
#pragma unroll
    for(int b=0;b<4;b++) acc[a][b]=(f32x4){0.f,0.f,0.f,0.f};

#pragma unroll
  for(int ks=0;ks<4;ks++){
    bf16x8 ah[4];
#pragma unroll
    for(int tm=0;tm<4;tm++){
      int m=wm*64+tm*16+(lane&15);
      ah[tm]=*(const bf16x8*)&Atile[0][m*128+(((ks*4)+q)^(m&15))*8];
    }
#pragma unroll
    for(int s=0;s<2;s++){
      const u16* Bb=PP+s*16384;
#pragma unroll
      for(int tn=0;tn<4;tn++){
        int n=wn*64+tn*16+(lane&15);
        bf16x8 bfr=*(const bf16x8*)&Bb[((size_t)ks*128+n)*32+q*8];
#pragma unroll
        for(int tm=0;tm<4;tm++)
          acc[tm][tn]=__builtin_amdgcn_mfma_f32_16x16x32_bf16(ah[tm],bfr,acc[tm][tn],0,0,0);
      }
    }
  }
#pragma unroll
  for(int ks=0;ks<4;ks++){
    bf16x8 al[4];
#pragma unroll
    for(int tm=0;tm<4;tm++){
      int m=wm*64+tm*16+(lane&15);
      al[tm]=*(const bf16x8*)&Atile[1][m*128+(((ks*4)+q)^(m&15))*8];
    }
#pragma unroll
    for(int tn=0;tn<4;tn++){
      int n=wn*64+tn*16+(lane&15);
      bf16x8 bfr=*(const bf16x8*)&PP[((size_t)ks*128+n)*32+q*8];
#pragma unroll
      for(int tm=0;tm<4;tm++)
        acc[tm][tn]=__builtin_amdgcn_mfma_f32_16x16x32_bf16(al[tm],bfr,acc[tm][tn],0,0,0);
    }
  }

  // ---- epilogue: +pb, hi/lo split into dead Atile (swz bits5-6), linear dwordx4 out ----
  __syncthreads();
  { u16* Sh=(u16*)Atile[0];
    u16* Sl=(u16*)Atile[1];
#pragma unroll
    for(int tn=0;tn<4;tn++){
      int n=wn*64+tn*16+(lane&15);
      float b=pb[n];
#pragma unroll
      for(int tm=0;tm<4;tm++){
        int rbase=wm*64+tm*16+q*4;
#pragma unroll
        for(int r=0;r<4;r++){
          float v=acc[tm][tn][r]+b;
          u16 hb=f2bf(v);
          u16 lb=f2bf(v-bf2f(hb));
          int row=rbase+r;
          u32 ab=(u32)(row*256+n*2);
          ab^=((u32)((row>>2)&3))<<5;
          Sh[ab>>1]=hb;
          Sl[ab>>1]=lb;
        }
      }
    }
  }
  __syncthreads();
  { const char* S0=(const char*)Atile[0];
    const char* S1=(const char*)Atile[1];
    char* xhb=(char*)(xh+(size_t)d0*HD);
    char* xlb=(char*)(xl+(size_t)d0*HD);
#pragma unroll
    for(int i=0;i<8;i++){
      u32 byte=(u32)(i*256+tid)*16;       // 32 KB tile, 16 lanes = one 256B row
      u32 row=byte>>8;
      u32 lb2=byte^((((row>>2)&3))<<5);
      *(uint4*)(xhb+byte)=*(const uint4*)(S0+lb2);
      *(uint4*)(xlb+byte)=*(const uint4*)(S1+lb2);
    }
  }
}

// ---------------- CSR build, key = (d>>5)*256 + et*32 + (d&31) ----------------
__global__ void count_deg2(const int* __restrict__ dst, const int* __restrict__ et,
                           u32* __restrict__ cnt){
  int e=blockIdx.x*256+threadIdx.x;
  int t=et[e];
  int d=dst[e];
  int key=(d>>5)*256 + t*32 + (d&31);
  atomicAdd(&cnt[key],1u);
}

__global__ void scan1(u32* __restrict__ cnt, u32* __restrict__ rp, u32* __restrict__ bsum){
  __shared__ u32 sh[256];
  int t=threadIdx.x; int base=blockIdx.x*256;
  u32 v=cnt[base+t]; sh[t]=v;
  cnt[base+t]=0u;                       // re-zero cur for scatter
  __syncthreads();
  for(int off=1;off<256;off<<=1){
    u32 tv=(t>=off)?sh[t-off]:0u; __syncthreads();
    sh[t]+=tv; __syncthreads();
  }
  rp[base+t]=sh[t]-v;
  if(t==255) bsum[blockIdx.x]=sh[255];
}

__global__ void scan2b(u32* __restrict__ bsum, u32* __restrict__ rp){
  __shared__ u32 sh[256];
  int t=threadIdx.x;
  u32 v0=bsum[t*4+0],v1=bsum[t*4+1],v2=bsum[t*4+2],v3=bsum[t*4+3];
  u32 s=v0+v1+v2+v3;
  sh[t]=s; __syncthreads();
  for(int off=1;off<256;off<<=1){
    u32 tv=(t>=off)?sh[t-off]:0u; __syncthreads();
    sh[t]+=tv; __syncthreads();
  }
  u32 ex=sh[t]-s;
  bsum[t*4+0]=ex; bsum[t*4+1]=ex+v0; bsum[t*4+2]=ex+v0+v1; bsum[t*4+3]=ex+v0+v1+v2;
  if(t==0) rp[NS]=NE;
  if(t==255) bsum[1024]=0u;
}

__global__ void scatter_edges2(const int* __restrict__ src, const int* __restrict__ dst,
                               const int* __restrict__ et, const u32* __restrict__ rp,
                               const u32* __restrict__ bsum,
                               u32* __restrict__ cur, u32* __restrict__ adj){
  int e=blockIdx.x*256+threadIdx.x;
  int t=et[e];
  int d=dst[e];
  int key=(d>>5)*256 + t*32 + (d&31);
  u32 pos=atomicAdd(&cur[key],1u);
  u32 row=(u32)((t<<5)|(d&31));                       // 8-bit local row
  adj[rp[key]+bsum[key>>8]+pos]=(u32)src[e] | (row<<15);
}

// ---------------- fused_layer v3: single-pass, 32-dst blocks ----------------
// A-tile: 256 rows (= 8 rel x 32 dst) x 128 cols, SINGLE bf16 plane, 64 KB.
// Gather: wave owns 64 keys (2 rels x 32 dsts) = rows [w*64,w*64+64); register
// accum with currow tracking; 32+32-deep UNGUARDED loads in one BB (adjv lanes
// >= nk are 0 -> tail loads hit x[0], PROC guarded). Rel-GEMM single-plane A,B
// (error enters /deg-damped path: ~4e-7, see round notes). Self-GEMM keeps full
// hi/lo A and B. LDS 64 KB -> 2 blocks/CU.
__global__ __launch_bounds__(256,2) void fused_layer(
    const u16* __restrict__ xh, const u16* __restrict__ xl,
    const u16* __restrict__ Bp,
    const u32* __restrict__ rp, const u32* __restrict__ bsum,
    const u32* __restrict__ adj,
    const float* __restrict__ sb, const int* __restrict__ mask,
    u16* __restrict__ oh, u16* __restrict__ ol, float* __restrict__ outf, int last)
{
  __shared__ u16 As16[256*128];     // 64 KB single-plane A; XOR-16 swizzled rows
  __shared__ float sdeg[32];
  const int tid=threadIdx.x;
  const int wave=tid>>6, lane=tid&63;
  const int q=lane>>4;
  const int d0=blockIdx.x*32;
  const u32* xh32=(const u32*)xh;

  // ---- zero own rows [w*64, w*64+64): 16 KB per wave ----
  { uint4 zz={0u,0u,0u,0u};
    uint4* p4=(uint4*)As16;
#pragma unroll
    for(int i=0;i<16;i++) p4[wave*1024 + i*64 + lane]=zz;
  }

  // ---- gather: wave's 64-key contiguous range, register accumulate ----
#define FLUSH1(rw) do{ \
    u32 u0=__float_as_uint(v0), u1=__float_as_uint(v1); \
    u32 hp=(u1&0xffff0000u)|(u0>>16); \
    int fw=(rw)*64 + (((lane>>2)^((rw)&15))<<2) + (lane&3); \
    ((u32*)As16)[fw]=hp; \
  }while(0)
  { u32 kb=(u32)(blockIdx.x*256 + wave*64);
    u32 beg=rp[kb]+bsum[kb>>8];
    u32 ke=kb+64u;
    u32 end=rp[ke]+bsum[ke>>8];
    int currow=-1; float v0=0.f,v1=0.f;
    for(u32 base=beg; base<end; base+=64u){
      int nk=(int)(end-base); if(nk>64) nk=64;
      u32 adjv=(lane<nk)?adj[base+lane]:0u;     // lanes >= nk -> 0 (x[0] tail loads)
      u32 hA[32], hB[32];
#pragma unroll
      for(int j=0;j<32;j++)
        hA[j]=xh32[(size_t)((u32)__builtin_amdgcn_readlane((int)adjv,j)&0x7fffu)*64+lane];
#pragma unroll
      for(int j=0;j<32;j++)
        hB[j]=xh32[(size_t)((u32)__builtin_amdgcn_readlane((int)adjv,j+32)&0x7fffu)*64+lane];
#pragma unroll
      for(int j=0;j<32;j++){
        if(j<nk){
          u32 w=(u32)__builtin_amdgcn_readlane((int)adjv,j);
          int r=(int)(w>>15);
          if(r!=currow){ if(currow>=0) FLUSH1(currow); currow=r; v0=0.f; v1=0.f; }
          v0+=bflo(hA[j]); v1+=bfhi(hA[j]);
        }
      }
#pragma unroll
      for(int j=0;j<32;j++){
        if(j+32<nk){
          u32 w=(u32)__builtin_amdgcn_readlane((int)adjv,j+32);
          int r=(int)(w>>15);
          if(r!=currow){ if(currow>=0) FLUSH1(currow); currow=r; v0=0.f; v1=0.f; }
          v0+=bflo(hB[j]); v1+=bfhi(hB[j]);
        }
      }
    }
    if(currow>=0) FLUSH1(currow);
  }
#undef FLUSH1
  __syncthreads();

  // ---- rel-GEMM: 8 rels, M=32 each, single-plane A and B, acc summed over rel ----
  f32x4 accR[2][2];
#pragma unroll
  for(int a=0;a<2;a++)
#pragma unroll
    for(int b=0;b<2;b++) accR[a][b]=(f32x4){0.f,0.f,0.f,0.f};
#pragma unroll
  for(int rl=0;rl<8;rl++){
    const u16* Bt=Bp+(size_t)rl*32768;
#pragma unroll
    for(int ks=0;ks<4;ks++){
      bf16x8 ah[2];
#pragma unroll
      for(int mf=0;mf<2;mf++){
        int ar=rl*32+mf*16+(lane&15);
        ah[mf]=*(const bf16x8*)&As16[ar*128+((((ks<<2)+q)^(ar&15))<<3)];
      }
#pragma unroll
      for(int tn=0;tn<2;tn++){
        int n=wave*32+tn*16+(lane&15);
        bf16x8 bh=*(const bf16x8*)&Bt[((size_t)(ks*128+n))*32+q*8];
#pragma unroll
        for(int mf=0;mf<2;mf++)
          accR[mf][tn]=__builtin_amdgcn_mfma_f32_16x16x32_bf16(ah[mf],bh,accR[mf][tn],0,0,0);
      }
    }
  }
  __syncthreads();

  // ---- self-stage: x rows d0..d0+31 hi -> A rows 0..31, lo -> rows 32..63; deg ----
#pragma unroll
  for(int i=0;i<2;i++){
    int rbase=wave*8+i*4;
    int r=rbase+(lane>>4);
    int g=(lane&15)^(r&15);
    gl_lds16(xh+(size_t)(d0+r)*HD+g*8, &As16[rbase*128]);
    gl_lds16(xl+(size_t)(d0+r)*HD+g*8, &As16[(32+rbase)*128]);
  }
  if(tid<32){
    int g=d0+tid; u32 dg=0;
#pragma unroll
    for(int et=0;et<8;et++){
      u32 k=(u32)(blockIdx.x*256 + et*32 + tid);
      dg+=(rp[k+1]+bsum[(k+1)>>8])-(rp[k]+bsum[k>>8]);
    }
    sdeg[tid]=1.f/fmaxf((float)dg,1.f);
  }
  __syncthreads();

  // ---- self-GEMM: full hi/lo A (rows 0..31 hi, 32..63 lo) x hi/lo B ----
  f32x4 accS[2][2];
#pragma unroll
  for(int a=0;a<2;a++)
#pragma unroll
    for(int b=0;b<2;b++) accS[a][b]=(f32x4){0.f,0.f,0.f,0.f};
  { const u16* Bt=Bp+(size_t)8*32768;
#pragma unroll
    for(int ks=0;ks<4;ks++){
      bf16x8 ah[2],al[2];
#pragma unroll
      for(int mf=0;mf<2;mf++){
        int ar=mf*16+(lane&15);
        int sw=((((ks<<2)+q)^(ar&15))<<3);
        ah[mf]=*(const bf16x8*)&As16[ar*128+sw];
        al[mf]=*(const bf16x8*)&As16[(32+ar)*128+sw];
      }
#pragma unroll
      for(int tn=0;tn<2;tn++){
        int n=wave*32+tn*16+(lane&15);
        size_t boff=((size_t)(ks*128+n))*32+q*8;
        bf16x8 bh=*(const bf16x8*)&Bt[boff];
        bf16x8 bl=*(const bf16x8*)&Bt[boff+16384];
#pragma unroll
        for(int mf=0;mf<2;mf++){
          accS[mf][tn]=__builtin_amdgcn_mfma_f32_16x16x32_bf16(ah[mf],bh,accS[mf][tn],0,0,0);
          accS[mf][tn]=__builtin_amdgcn_mfma_f32_16x16x32_bf16(al[mf],bh,accS[mf][tn],0,0,0);
          accS[mf][tn]=__builtin_amdgcn_mfma_f32_16x16x32_bf16(ah[mf],bl,accS[mf][tn],0,0,0);
        }
      }
    }
  }

  // ---- epilogue: out = relu(accS + sb + accR/deg); C/D: col=lane&15, row=q*4+reg ----
#pragma unroll
  for(int tn=0;tn<2;tn++){
    int n=wave*32+tn*16+(lane&15);
    float bb=sb[n];
    if(last){
#pragma unroll
      for(int mf=0;mf<2;mf++)
#pragma unroll
        for(int rr=0;rr<4;rr++){
          int row=mf*16+q*4+rr;
          float v=fmaxf(accS[mf][tn][rr]+bb+accR[mf][tn][rr]*sdeg[row],0.f);
          v*=(float)mask[d0+row];
          outf[(size_t)(d0+row)*HD+n]=v;
        }
    } else {
#pragma unroll
      for(int mf=0;mf<2;mf++)
#pragma unroll
        for(int rr=0;rr<4;rr++){
          int row=mf*16+q*4+rr;
          float v=fmaxf(accS[mf][tn][rr]+bb+accR[mf][tn][rr]*sdeg[row],0.f);
          u16 hb=f2bf(v);
          u16 lb=f2bf(v-bf2f(hb));
          oh[(size_t)(d0+row)*HD+n]=hb;
          ol[(size_t)(d0+row)*HD+n]=lb;
        }
    }
  }
}

extern "C" void kernel_launch(void* const* d_in, const int* in_sizes, int n_in,
                              void* d_out, int out_size, void* d_ws, size_t ws_size,
                              hipStream_t stream)
{
  (void)in_sizes; (void)n_in; (void)out_size; (void)ws_size;
  const int*   cid =(const int*)  d_in[0];
  const int*   kid =(const int*)  d_in[1];
  const int*   mask=(const int*)  d_in[2];
  const int*   ei  =(const int*)  d_in[3];
  const int*   et  =(const int*)  d_in[4];
  const float* cemb=(const float*)d_in[5];
  const float* kemb=(const float*)d_in[6];
  const float* pW  =(const float*)d_in[7];
  const float* pb  =(const float*)d_in[8];
  const float* sW  =(const float*)d_in[9];
  const float* sb  =(const float*)d_in[10];
  const float* rW  =(const float*)d_in[11];
  float* out=(float*)d_out;
  char*  ws =(char*)d_ws;

  u16* xh =(u16*)(ws+XH_OFF);
  u16* xl =(u16*)(ws+XL_OFF);
  u16* xh2=(u16*)(ws+XH2_OFF);
  u16* xl2=(u16*)(ws+XL2_OFF);
  u32* adj =(u32*)(ws+ADJ_OFF);
  u32* rp  =(u32*)(ws+RP_OFF);
  u32* cur =(u32*)(ws+CUR_OFF);
  u32* bsum=(u32*)(ws+BSUM_OFF);
  u16* Bp  =(u16*)(ws+BP_OFF);
  const int* srcA=ei;
  const int* dstA=ei+NE;

  hipMemsetAsync(cur,0,NS*sizeof(u32),stream);
  prep_w<<<1216,256,0,stream>>>(rW,sW,pW,Bp);
  embed_mfma<<<NODES/128,256,0,stream>>>(cid,kid,cemb,kemb,Bp+PP_ELEM,pb,xh,xl);
  count_deg2<<<NE/256,256,0,stream>>>(dstA,et,cur);
  scan1<<<NS/256,256,0,stream>>>(cur,rp,bsum);
  scan2b<<<1,256,0,stream>>>(bsum,rp);
  scatter_edges2<<<NE/256,256,0,stream>>>(srcA,dstA,et,rp,bsum,cur,adj);

  fused_layer<<<NODES/32,256,0,stream>>>(xh,xl,Bp,rp,bsum,adj,sb,mask,xh2,xl2,out,0);
  fused_layer<<<NODES/32,256,0,stream>>>(xh2,xl2,Bp+BP_LAYER,rp,bsum,adj,sb+HD,mask,xh,xl,out,1);
}